// Round 16
// baseline (561.726 us; speedup 1.0000x reference)
//
#include <hip/hip_runtime.h>
#include <hip/hip_fp16.h>
#include <math.h>

#define N_NODES   100000
#define N_EDGES   1600000
#define N_FEAT    64
#define HIDDEN    64
#define BIOPRINT  2048
#define N_GRAPHS  1024

#define SCAN_BLK  1024
#define N_SCAN_BLOCKS ((N_NODES + SCAN_BLK - 1) / SCAN_BLK)   // 98
#define FILL_SLICE 50000                                       // 2 passes

typedef __attribute__((ext_vector_type(4))) int i32x4;

__device__ __forceinline__ __half2 shx_h2(__half2 v, int m) {
    int x = __shfl_xor(*(int*)&v, m);
    return *(__half2*)&x;
}

// ---------------- degree: 4 edges/thread ----------------

__global__ void k_deg(const int* __restrict__ dst, int* __restrict__ deg, int n4) {
    int i = blockIdx.x * blockDim.x + threadIdx.x;
    if (i < n4) {
        i32x4 d = __builtin_nontemporal_load(&((const i32x4*)dst)[i]);
        atomicAdd(&deg[d.x], 1);
        atomicAdd(&deg[d.y], 1);
        atomicAdd(&deg[d.z], 1);
        atomicAdd(&deg[d.w], 1);
    }
}

// ---------------- CSR build: scan1 (+dinv), scan3 (+inline bsum scan, +gstart) ----------------

__global__ __launch_bounds__(SCAN_BLK) void k_scan1(
        const int* __restrict__ deg, int* __restrict__ incl,
        int* __restrict__ bsum, float* __restrict__ dinv, int n) {
    __shared__ int tmp[SCAN_BLK];
    int t = threadIdx.x;
    int i = blockIdx.x * SCAN_BLK + t;
    int v = (i < n) ? deg[i] : 0;
    if (i < n) dinv[i] = rsqrtf((float)v + 1.0f);
    tmp[t] = v;
    __syncthreads();
    for (int off = 1; off < SCAN_BLK; off <<= 1) {
        int u = (t >= off) ? tmp[t - off] : 0;
        __syncthreads();
        tmp[t] += u;
        __syncthreads();
    }
    if (i < n) incl[i] = tmp[t];
    if (t == SCAN_BLK - 1) bsum[blockIdx.x] = tmp[t];
}

__global__ __launch_bounds__(SCAN_BLK) void k_scan3(
        int* __restrict__ rowptr, const int* __restrict__ deg,
        const int* __restrict__ bsum, int* __restrict__ cursor,
        const int* __restrict__ batch, int* __restrict__ gstart, int n) {
    int t = threadIdx.x;
    int bid = blockIdx.x;
    if (bid >= N_SCAN_BLOCKS) {
        int g = (bid - N_SCAN_BLOCKS) * SCAN_BLK + t;
        if (g > N_GRAPHS) return;
        if (g == N_GRAPHS) { gstart[g] = N_NODES; return; }
        int lo = 0, hi = N_NODES;
        while (lo < hi) { int mid = (lo + hi) >> 1; if (batch[mid] < g) lo = mid + 1; else hi = mid; }
        gstart[g] = lo;
        return;
    }
    __shared__ int sb[128];
    if (t < 128) sb[t] = (t < N_SCAN_BLOCKS) ? bsum[t] : 0;
    __syncthreads();
    for (int off = 1; off < 128; off <<= 1) {
        int u = (t >= off && t < 128) ? sb[t - off] : 0;
        __syncthreads();
        if (t < 128) sb[t] += u;
        __syncthreads();
    }
    int base = (bid == 0) ? 0 : sb[bid - 1];
    int i = bid * SCAN_BLK + t;
    if (i < n) {
        int ex = rowptr[i] - deg[i] + base;
        rowptr[i] = ex;
        cursor[i] = ex;
    }
    if (i == 0) rowptr[n] = N_EDGES;
}

// fill pass: 4 edges/thread; range-filtered so the write slice stays L2-resident
__global__ void k_fillp(const int* __restrict__ src, const int* __restrict__ dst,
                        int* __restrict__ cursor, int* __restrict__ col,
                        int lo, int hi, int n4) {
    int i = blockIdx.x * blockDim.x + threadIdx.x;
    if (i < n4) {
        i32x4 d = __builtin_nontemporal_load(&((const i32x4*)dst)[i]);
        i32x4 s = __builtin_nontemporal_load(&((const i32x4*)src)[i]);
        if (d.x >= lo && d.x < hi) col[atomicAdd(&cursor[d.x], 1)] = s.x;
        if (d.y >= lo && d.y < hi) col[atomicAdd(&cursor[d.y], 1)] = s.y;
        if (d.z >= lo && d.z < hi) col[atomicAdd(&cursor[d.z], 1)] = s.z;
        if (d.w >= lo && d.w < hi) col[atomicAdd(&cursor[d.w], 1)] = s.w;
    }
}

// ---------------- layer-1 matmul: hw1' = fp16[(x @ W1) * dinv] ----------------
__global__ __launch_bounds__(256) void k_mm(
        const float* __restrict__ h, const float* __restrict__ W,
        const float* __restrict__ dinv, __half* __restrict__ hw) {
    __shared__ float sW[64 * 64];
    __shared__ float sH[4 * 64];
    int t = threadIdx.x;
    const float4* W4 = (const float4*)W;
    float4* sW4 = (float4*)sW;
    for (int i = t; i < 1024; i += 256) sW4[i] = W4[i];
    int row0 = blockIdx.x * 4;
    int r = t >> 6, j = t & 63;
    sH[r * 64 + j] = h[(row0 + r) * 64 + j];
    __syncthreads();
    int i = row0 + r;
    float sum = 0.0f;
#pragma unroll
    for (int k = 0; k < 64; ++k) sum = fmaf(sH[r * 64 + k], sW[k * 64 + j], sum);
    hw[i * 64 + j] = __float2half_rn(sum * dinv[i]);
}

// ---------------- gather core: 4 nodes per wave, 2 slots/node, 4 loads in flight ----------------
__device__ __forceinline__ void gather2x4(
        const int* __restrict__ col, const uint4* __restrict__ hv,
        int rs, int re, int slot, int sub, float f[8]) {
    __half2 a0 = __float2half2_rn(0.f), a1 = a0, a2 = a0, a3 = a0;
    __half2 c0 = a0, c1 = a0, c2 = a0, c3 = a0;
    int e = rs;
    for (; e + 8 <= re; e += 8) {
        int s0 = __builtin_nontemporal_load(&col[e + slot]);
        int s1 = __builtin_nontemporal_load(&col[e + 2 + slot]);
        int s2 = __builtin_nontemporal_load(&col[e + 4 + slot]);
        int s3 = __builtin_nontemporal_load(&col[e + 6 + slot]);
        uint4 u0 = hv[(size_t)s0 * 8 + sub];
        uint4 u1 = hv[(size_t)s1 * 8 + sub];
        uint4 u2 = hv[(size_t)s2 * 8 + sub];
        uint4 u3 = hv[(size_t)s3 * 8 + sub];
        a0 = __hadd2(a0, *(__half2*)&u0.x); a1 = __hadd2(a1, *(__half2*)&u0.y);
        a2 = __hadd2(a2, *(__half2*)&u0.z); a3 = __hadd2(a3, *(__half2*)&u0.w);
        c0 = __hadd2(c0, *(__half2*)&u1.x); c1 = __hadd2(c1, *(__half2*)&u1.y);
        c2 = __hadd2(c2, *(__half2*)&u1.z); c3 = __hadd2(c3, *(__half2*)&u1.w);
        a0 = __hadd2(a0, *(__half2*)&u2.x); a1 = __hadd2(a1, *(__half2*)&u2.y);
        a2 = __hadd2(a2, *(__half2*)&u2.z); a3 = __hadd2(a3, *(__half2*)&u2.w);
        c0 = __hadd2(c0, *(__half2*)&u3.x); c1 = __hadd2(c1, *(__half2*)&u3.y);
        c2 = __hadd2(c2, *(__half2*)&u3.z); c3 = __hadd2(c3, *(__half2*)&u3.w);
    }
    for (; e + slot < re; e += 2) {
        int s0 = col[e + slot];
        uint4 u0 = hv[(size_t)s0 * 8 + sub];
        a0 = __hadd2(a0, *(__half2*)&u0.x); a1 = __hadd2(a1, *(__half2*)&u0.y);
        a2 = __hadd2(a2, *(__half2*)&u0.z); a3 = __hadd2(a3, *(__half2*)&u0.w);
    }
    a0 = __hadd2(a0, c0); a1 = __hadd2(a1, c1);
    a2 = __hadd2(a2, c2); a3 = __hadd2(a3, c3);
    a0 = __hadd2(a0, shx_h2(a0, 8));
    a1 = __hadd2(a1, shx_h2(a1, 8));
    a2 = __hadd2(a2, shx_h2(a2, 8));
    a3 = __hadd2(a3, shx_h2(a3, 8));
    float2 f0 = __half22float2(a0), f1 = __half22float2(a1);
    float2 f2 = __half22float2(a2), f3 = __half22float2(a3);
    f[0] = f0.x; f[1] = f0.y; f[2] = f1.x; f[3] = f1.y;
    f[4] = f2.x; f[5] = f2.y; f[6] = f3.x; f[7] = f3.y;
}

// ---------------- fused gather(4 nodes/wave) + relu + LDS matmul ----------------
__global__ __launch_bounds__(256) void k_gmm(
        const int* __restrict__ rowptr, const int* __restrict__ col,
        const float* __restrict__ dinv, const float* __restrict__ b,
        const __half* __restrict__ hw_in, const float* __restrict__ W,
        __half* __restrict__ hw_out) {
    __shared__ float sW[64 * 64];
    __shared__ float sA[16 * 64];
    int t = threadIdx.x;
    const float4* W4 = (const float4*)W;
    float4* sW4 = (float4*)sW;
    for (int i = t; i < 1024; i += 256) sW4[i] = W4[i];
    __syncthreads();

    int wave = t >> 6, lane = t & 63;
    int quarter = lane >> 4, slot = (lane >> 3) & 1, sub = lane & 7;
    int i0 = blockIdx.x * 16 + wave * 4;
    int i = i0 + quarter;
    float di = dinv[i];
    int rs = rowptr[i], re = rowptr[i + 1];
    const uint4* hv = (const uint4*)hw_in;

    float f[8];
    gather2x4(col, hv, rs, re, slot, sub, f);

    uint4 us = hv[(size_t)i * 8 + sub];
    float2 s0 = __half22float2(*(__half2*)&us.x);
    float2 s1 = __half22float2(*(__half2*)&us.y);
    float2 s2 = __half22float2(*(__half2*)&us.z);
    float2 s3 = __half22float2(*(__half2*)&us.w);
    float sf[8] = {s0.x, s0.y, s1.x, s1.y, s2.x, s2.y, s3.x, s3.y};
    float4 ba = ((const float4*)b)[sub * 2];
    float4 bb = ((const float4*)b)[sub * 2 + 1];
    float bf[8] = {ba.x, ba.y, ba.z, ba.w, bb.x, bb.y, bb.z, bb.w};
    if (slot == 0) {
        float r[8];
#pragma unroll
        for (int k = 0; k < 8; ++k) r[k] = fmaxf(fmaf(di, f[k] + sf[k], bf[k]), 0.f);
        *(float4*)&sA[(wave * 4 + quarter) * 64 + sub * 8]     = make_float4(r[0], r[1], r[2], r[3]);
        *(float4*)&sA[(wave * 4 + quarter) * 64 + sub * 8 + 4] = make_float4(r[4], r[5], r[6], r[7]);
    }

#pragma unroll
    for (int h = 0; h < 4; ++h) {
        const float4* sA4 = (const float4*)&sA[(wave * 4 + h) * 64];
        float sum = 0.f;
#pragma unroll
        for (int k4 = 0; k4 < 16; ++k4) {
            float4 a4 = sA4[k4];
            sum = fmaf(a4.x, sW[(k4 * 4 + 0) * 64 + lane], sum);
            sum = fmaf(a4.y, sW[(k4 * 4 + 1) * 64 + lane], sum);
            sum = fmaf(a4.z, sW[(k4 * 4 + 2) * 64 + lane], sum);
            sum = fmaf(a4.w, sW[(k4 * 4 + 3) * 64 + lane], sum);
        }
        hw_out[(size_t)(i0 + h) * 64 + lane] = __float2half_rn(sum * dinv[i0 + h]);
    }
}

// ---------------- layer-3 gather (4 nodes/wave; fp16 conv out) ----------------
__global__ __launch_bounds__(256) void k_gather3(
        const int* __restrict__ rowptr, const int* __restrict__ col,
        const float* __restrict__ dinv, const float* __restrict__ b,
        const __half* __restrict__ hw_in, __half* __restrict__ conv) {
    int t = threadIdx.x;
    int wave = t >> 6, lane = t & 63;
    int quarter = lane >> 4, slot = (lane >> 3) & 1, sub = lane & 7;
    int i = blockIdx.x * 16 + wave * 4 + quarter;
    float di = dinv[i];
    int rs = rowptr[i], re = rowptr[i + 1];
    const uint4* hv = (const uint4*)hw_in;

    float f[8];
    gather2x4(col, hv, rs, re, slot, sub, f);

    if (slot == 0) {
        uint4 us = hv[(size_t)i * 8 + sub];
        float2 s0 = __half22float2(*(__half2*)&us.x);
        float2 s1 = __half22float2(*(__half2*)&us.y);
        float2 s2 = __half22float2(*(__half2*)&us.z);
        float2 s3 = __half22float2(*(__half2*)&us.w);
        float sf[8] = {s0.x, s0.y, s1.x, s1.y, s2.x, s2.y, s3.x, s3.y};
        float4 ba = ((const float4*)b)[sub * 2];
        float4 bb = ((const float4*)b)[sub * 2 + 1];
        float bf[8] = {ba.x, ba.y, ba.z, ba.w, bb.x, bb.y, bb.z, bb.w};
        uint4 o;
        __half2* oh = (__half2*)&o;
#pragma unroll
        for (int c = 0; c < 4; ++c) {
            float r0 = fmaf(di, f[2 * c] + sf[2 * c], bf[2 * c]);
            float r1 = fmaf(di, f[2 * c + 1] + sf[2 * c + 1], bf[2 * c + 1]);
            oh[c] = __halves2half2(__float2half_rn(r0), __float2half_rn(r1));
        }
        ((uint4*)conv)[(size_t)i * 8 + sub] = o;
    }
}

// ---------------- fused mean-pool + dense + softmax + threshold: 8 graphs/block ----------------
__global__ __launch_bounds__(256) void k_dense(
        const __half* __restrict__ conv, const int* __restrict__ gstart,
        const float* __restrict__ Wd, const float* __restrict__ bd,
        float* __restrict__ out) {
    __shared__ float sp[8][64];
    __shared__ float red[8][4];
    int t = threadIdx.x;
    int wave = t >> 6, lane = t & 63;
    int g0 = blockIdx.x * 8;
#pragma unroll
    for (int gg = 0; gg < 2; ++gg) {
        int g = wave * 2 + gg;
        int n0 = gstart[g0 + g], n1 = gstart[g0 + g + 1];
        float acc = 0.f;
        int i = n0;
        for (; i + 1 < n1; i += 2) {
            float v0 = __half2float(conv[(size_t)i * 64 + lane]);
            float v1 = __half2float(conv[(size_t)(i + 1) * 64 + lane]);
            acc += v0 + v1;
        }
        if (i < n1) acc += __half2float(conv[(size_t)i * 64 + lane]);
        int n = n1 - n0;
        sp[g][lane] = (n > 0) ? acc / (float)n : 0.f;
    }
    __syncthreads();

    float acc[8][8];
#pragma unroll
    for (int r = 0; r < 8; ++r) {
        float bv = bd[r * 256 + t];
#pragma unroll
        for (int g = 0; g < 8; ++g) acc[g][r] = bv;
    }
    for (int k = 0; k < 64; ++k) {
        float w[8];
#pragma unroll
        for (int r = 0; r < 8; ++r) w[r] = Wd[k * BIOPRINT + r * 256 + t];
#pragma unroll
        for (int g = 0; g < 8; ++g) {
            float h = sp[g][k];
#pragma unroll
            for (int r = 0; r < 8; ++r) acc[g][r] = fmaf(h, w[r], acc[g][r]);
        }
    }
    float gm[8];
#pragma unroll
    for (int g = 0; g < 8; ++g) {
        float m = acc[g][0];
#pragma unroll
        for (int r = 1; r < 8; ++r) m = fmaxf(m, acc[g][r]);
#pragma unroll
        for (int off = 32; off > 0; off >>= 1) m = fmaxf(m, __shfl_xor(m, off));
        if (lane == 0) red[g][wave] = m;
    }
    __syncthreads();
#pragma unroll
    for (int g = 0; g < 8; ++g)
        gm[g] = fmaxf(fmaxf(red[g][0], red[g][1]), fmaxf(red[g][2], red[g][3]));
    __syncthreads();
    float gs[8];
#pragma unroll
    for (int g = 0; g < 8; ++g) {
        float s = 0.f;
#pragma unroll
        for (int r = 0; r < 8; ++r) { acc[g][r] = expf(acc[g][r] - gm[g]); s += acc[g][r]; }
#pragma unroll
        for (int off = 32; off > 0; off >>= 1) s += __shfl_xor(s, off);
        if (lane == 0) red[g][wave] = s;
    }
    __syncthreads();
#pragma unroll
    for (int g = 0; g < 8; ++g)
        gs[g] = red[g][0] + red[g][1] + red[g][2] + red[g][3];
#pragma unroll
    for (int g = 0; g < 8; ++g)
#pragma unroll
        for (int r = 0; r < 8; ++r) {
            float p = acc[g][r] / gs[g];
            out[(size_t)(g0 + g) * BIOPRINT + r * 256 + t] = (p >= 0.5f) ? 1.0f : 0.0f;
        }
}

// ---------------- launch ----------------

extern "C" void kernel_launch(void* const* d_in, const int* in_sizes, int n_in,
                              void* d_out, int out_size, void* d_ws, size_t ws_size,
                              hipStream_t stream) {
    const float* x     = (const float*)d_in[0];
    const int*   ei    = (const int*)d_in[1];
    const int*   batch = (const int*)d_in[2];
    const float* W1 = (const float*)d_in[3];
    const float* b1 = (const float*)d_in[4];
    const float* W2 = (const float*)d_in[5];
    const float* b2 = (const float*)d_in[6];
    const float* W3 = (const float*)d_in[7];
    const float* b3 = (const float*)d_in[8];
    const float* Wd = (const float*)d_in[9];
    const float* bd = (const float*)d_in[10];
    float* out = (float*)d_out;

    const int* src = ei;
    const int* dst = ei + N_EDGES;

    char* ws = (char*)d_ws;
    size_t off = 0;
    auto alloc = [&](size_t bytes) {
        void* p = ws + off;
        off += (bytes + 255) & ~(size_t)255;
        return p;
    };
    int*    deg    = (int*)alloc(N_NODES * sizeof(int));
    float*  dinv   = (float*)alloc(N_NODES * sizeof(float));
    int*    rowptr = (int*)alloc((N_NODES + 1) * sizeof(int));
    int*    bsum   = (int*)alloc(128 * sizeof(int));
    int*    cursor = (int*)alloc(N_NODES * sizeof(int));
    int*    gstart = (int*)alloc((N_GRAPHS + 1) * sizeof(int));
    int*    col    = (int*)alloc((size_t)N_EDGES * sizeof(int));
    __half* bufA   = (__half*)alloc((size_t)N_NODES * HIDDEN * sizeof(__half));
    __half* bufB   = (__half*)alloc((size_t)N_NODES * HIDDEN * sizeof(__half));
    __half* conv   = (__half*)alloc((size_t)N_NODES * HIDDEN * sizeof(__half));

    hipMemsetAsync(deg, 0, N_NODES * sizeof(int), stream);

    k_deg<<<(N_EDGES / 4 + 255) / 256, 256, 0, stream>>>(dst, deg, N_EDGES / 4);
    k_scan1<<<N_SCAN_BLOCKS, SCAN_BLK, 0, stream>>>(deg, rowptr, bsum, dinv, N_NODES);
    k_scan3<<<N_SCAN_BLOCKS + 2, SCAN_BLK, 0, stream>>>(rowptr, deg, bsum, cursor,
                                                        batch, gstart, N_NODES);
    for (int p = 0; p < 2; ++p) {
        k_fillp<<<(N_EDGES / 4 + 255) / 256, 256, 0, stream>>>(
            src, dst, cursor, col, p * FILL_SLICE, (p + 1) * FILL_SLICE, N_EDGES / 4);
    }

    const int mm_grid  = N_NODES / 4;          // 25000
    const int g16_grid = N_NODES / 16;         // 6250 (16 nodes/block)
    k_mm<<<mm_grid, 256, 0, stream>>>(x, W1, dinv, bufA);
    k_gmm<<<g16_grid, 256, 0, stream>>>(rowptr, col, dinv, b1, bufA, W2, bufB);
    k_gmm<<<g16_grid, 256, 0, stream>>>(rowptr, col, dinv, b2, bufB, W3, bufA);
    k_gather3<<<g16_grid, 256, 0, stream>>>(rowptr, col, dinv, b3, bufA, conv);
    k_dense<<<N_GRAPHS / 8, 256, 0, stream>>>(conv, gstart, Wd, bd, out);
}

// Round 17
// 522.270 us; speedup vs baseline: 1.0755x; 1.0755x over previous
//
#include <hip/hip_runtime.h>
#include <hip/hip_fp16.h>
#include <math.h>

#define N_NODES   100000
#define N_EDGES   1600000
#define N_FEAT    64
#define HIDDEN    64
#define BIOPRINT  2048
#define N_GRAPHS  1024

#define SCAN_BLK  1024
#define N_SCAN_BLOCKS ((N_NODES + SCAN_BLK - 1) / SCAN_BLK)   // 98
#define FILL_SLICE 50000                                       // 2 passes

__device__ __forceinline__ __half2 shx_h2(__half2 v, int m) {
    int x = __shfl_xor(*(int*)&v, m);
    return *(__half2*)&x;
}

// ---------------- degree: 1 edge/thread (max waves in flight — scatter is latency-bound) ----------------

__global__ void k_deg(const int* __restrict__ dst, int* __restrict__ deg, int n) {
    int i = blockIdx.x * blockDim.x + threadIdx.x;
    if (i < n) atomicAdd(&deg[__builtin_nontemporal_load(&dst[i])], 1);
}

// ---------------- CSR build: scan1 (+dinv), scan3 (+inline bsum scan, +gstart) ----------------

__global__ __launch_bounds__(SCAN_BLK) void k_scan1(
        const int* __restrict__ deg, int* __restrict__ incl,
        int* __restrict__ bsum, float* __restrict__ dinv, int n) {
    __shared__ int tmp[SCAN_BLK];
    int t = threadIdx.x;
    int i = blockIdx.x * SCAN_BLK + t;
    int v = (i < n) ? deg[i] : 0;
    if (i < n) dinv[i] = rsqrtf((float)v + 1.0f);
    tmp[t] = v;
    __syncthreads();
    for (int off = 1; off < SCAN_BLK; off <<= 1) {
        int u = (t >= off) ? tmp[t - off] : 0;
        __syncthreads();
        tmp[t] += u;
        __syncthreads();
    }
    if (i < n) incl[i] = tmp[t];
    if (t == SCAN_BLK - 1) bsum[blockIdx.x] = tmp[t];
}

__global__ __launch_bounds__(SCAN_BLK) void k_scan3(
        int* __restrict__ rowptr, const int* __restrict__ deg,
        const int* __restrict__ bsum, int* __restrict__ cursor,
        const int* __restrict__ batch, int* __restrict__ gstart, int n) {
    int t = threadIdx.x;
    int bid = blockIdx.x;
    if (bid >= N_SCAN_BLOCKS) {
        int g = (bid - N_SCAN_BLOCKS) * SCAN_BLK + t;
        if (g > N_GRAPHS) return;
        if (g == N_GRAPHS) { gstart[g] = N_NODES; return; }
        int lo = 0, hi = N_NODES;
        while (lo < hi) { int mid = (lo + hi) >> 1; if (batch[mid] < g) lo = mid + 1; else hi = mid; }
        gstart[g] = lo;
        return;
    }
    __shared__ int sb[128];
    if (t < 128) sb[t] = (t < N_SCAN_BLOCKS) ? bsum[t] : 0;
    __syncthreads();
    for (int off = 1; off < 128; off <<= 1) {
        int u = (t >= off && t < 128) ? sb[t - off] : 0;
        __syncthreads();
        if (t < 128) sb[t] += u;
        __syncthreads();
    }
    int base = (bid == 0) ? 0 : sb[bid - 1];
    int i = bid * SCAN_BLK + t;
    if (i < n) {
        int ex = rowptr[i] - deg[i] + base;
        rowptr[i] = ex;
        cursor[i] = ex;
    }
    if (i == 0) rowptr[n] = N_EDGES;
}

// fill pass: 1 edge/thread; range-filtered so the write slice stays L2-resident
__global__ void k_fillp(const int* __restrict__ src, const int* __restrict__ dst,
                        int* __restrict__ cursor, int* __restrict__ col,
                        int lo, int hi, int n) {
    int e = blockIdx.x * blockDim.x + threadIdx.x;
    if (e < n) {
        int d = __builtin_nontemporal_load(&dst[e]);
        if (d >= lo && d < hi) {
            int s = __builtin_nontemporal_load(&src[e]);
            int pos = atomicAdd(&cursor[d], 1);
            col[pos] = s;
        }
    }
}

// ---------------- layer-1 matmul: hw1' = fp16[(x @ W1) * dinv] ----------------
__global__ __launch_bounds__(256) void k_mm(
        const float* __restrict__ h, const float* __restrict__ W,
        const float* __restrict__ dinv, __half* __restrict__ hw) {
    __shared__ float sW[64 * 64];
    __shared__ float sH[4 * 64];
    int t = threadIdx.x;
    const float4* W4 = (const float4*)W;
    float4* sW4 = (float4*)sW;
    for (int i = t; i < 1024; i += 256) sW4[i] = W4[i];
    int row0 = blockIdx.x * 4;
    int r = t >> 6, j = t & 63;
    sH[r * 64 + j] = h[(row0 + r) * 64 + j];
    __syncthreads();
    int i = row0 + r;
    float sum = 0.0f;
#pragma unroll
    for (int k = 0; k < 64; ++k) sum = fmaf(sH[r * 64 + k], sW[k * 64 + j], sum);
    hw[i * 64 + j] = __float2half_rn(sum * dinv[i]);
}

// ---------------- gather core: 4 nodes per wave, 2 slots/node, 4 loads in flight ----------------
__device__ __forceinline__ void gather2x4(
        const int* __restrict__ col, const uint4* __restrict__ hv,
        int rs, int re, int slot, int sub, float f[8]) {
    __half2 a0 = __float2half2_rn(0.f), a1 = a0, a2 = a0, a3 = a0;
    __half2 c0 = a0, c1 = a0, c2 = a0, c3 = a0;
    int e = rs;
    for (; e + 8 <= re; e += 8) {
        int s0 = __builtin_nontemporal_load(&col[e + slot]);
        int s1 = __builtin_nontemporal_load(&col[e + 2 + slot]);
        int s2 = __builtin_nontemporal_load(&col[e + 4 + slot]);
        int s3 = __builtin_nontemporal_load(&col[e + 6 + slot]);
        uint4 u0 = hv[(size_t)s0 * 8 + sub];
        uint4 u1 = hv[(size_t)s1 * 8 + sub];
        uint4 u2 = hv[(size_t)s2 * 8 + sub];
        uint4 u3 = hv[(size_t)s3 * 8 + sub];
        a0 = __hadd2(a0, *(__half2*)&u0.x); a1 = __hadd2(a1, *(__half2*)&u0.y);
        a2 = __hadd2(a2, *(__half2*)&u0.z); a3 = __hadd2(a3, *(__half2*)&u0.w);
        c0 = __hadd2(c0, *(__half2*)&u1.x); c1 = __hadd2(c1, *(__half2*)&u1.y);
        c2 = __hadd2(c2, *(__half2*)&u1.z); c3 = __hadd2(c3, *(__half2*)&u1.w);
        a0 = __hadd2(a0, *(__half2*)&u2.x); a1 = __hadd2(a1, *(__half2*)&u2.y);
        a2 = __hadd2(a2, *(__half2*)&u2.z); a3 = __hadd2(a3, *(__half2*)&u2.w);
        c0 = __hadd2(c0, *(__half2*)&u3.x); c1 = __hadd2(c1, *(__half2*)&u3.y);
        c2 = __hadd2(c2, *(__half2*)&u3.z); c3 = __hadd2(c3, *(__half2*)&u3.w);
    }
    for (; e + slot < re; e += 2) {
        int s0 = col[e + slot];
        uint4 u0 = hv[(size_t)s0 * 8 + sub];
        a0 = __hadd2(a0, *(__half2*)&u0.x); a1 = __hadd2(a1, *(__half2*)&u0.y);
        a2 = __hadd2(a2, *(__half2*)&u0.z); a3 = __hadd2(a3, *(__half2*)&u0.w);
    }
    a0 = __hadd2(a0, c0); a1 = __hadd2(a1, c1);
    a2 = __hadd2(a2, c2); a3 = __hadd2(a3, c3);
    a0 = __hadd2(a0, shx_h2(a0, 8));
    a1 = __hadd2(a1, shx_h2(a1, 8));
    a2 = __hadd2(a2, shx_h2(a2, 8));
    a3 = __hadd2(a3, shx_h2(a3, 8));
    float2 f0 = __half22float2(a0), f1 = __half22float2(a1);
    float2 f2 = __half22float2(a2), f3 = __half22float2(a3);
    f[0] = f0.x; f[1] = f0.y; f[2] = f1.x; f[3] = f1.y;
    f[4] = f2.x; f[5] = f2.y; f[6] = f3.x; f[7] = f3.y;
}

// ---------------- fused gather(4 nodes/wave) + relu + LDS matmul ----------------
__global__ __launch_bounds__(256) void k_gmm(
        const int* __restrict__ rowptr, const int* __restrict__ col,
        const float* __restrict__ dinv, const float* __restrict__ b,
        const __half* __restrict__ hw_in, const float* __restrict__ W,
        __half* __restrict__ hw_out) {
    __shared__ float sW[64 * 64];
    __shared__ float sA[16 * 64];
    int t = threadIdx.x;
    const float4* W4 = (const float4*)W;
    float4* sW4 = (float4*)sW;
    for (int i = t; i < 1024; i += 256) sW4[i] = W4[i];
    __syncthreads();

    int wave = t >> 6, lane = t & 63;
    int quarter = lane >> 4, slot = (lane >> 3) & 1, sub = lane & 7;
    int i0 = blockIdx.x * 16 + wave * 4;
    int i = i0 + quarter;
    float di = dinv[i];
    int rs = rowptr[i], re = rowptr[i + 1];
    const uint4* hv = (const uint4*)hw_in;

    float f[8];
    gather2x4(col, hv, rs, re, slot, sub, f);

    uint4 us = hv[(size_t)i * 8 + sub];
    float2 s0 = __half22float2(*(__half2*)&us.x);
    float2 s1 = __half22float2(*(__half2*)&us.y);
    float2 s2 = __half22float2(*(__half2*)&us.z);
    float2 s3 = __half22float2(*(__half2*)&us.w);
    float sf[8] = {s0.x, s0.y, s1.x, s1.y, s2.x, s2.y, s3.x, s3.y};
    float4 ba = ((const float4*)b)[sub * 2];
    float4 bb = ((const float4*)b)[sub * 2 + 1];
    float bf[8] = {ba.x, ba.y, ba.z, ba.w, bb.x, bb.y, bb.z, bb.w};
    if (slot == 0) {
        float r[8];
#pragma unroll
        for (int k = 0; k < 8; ++k) r[k] = fmaxf(fmaf(di, f[k] + sf[k], bf[k]), 0.f);
        *(float4*)&sA[(wave * 4 + quarter) * 64 + sub * 8]     = make_float4(r[0], r[1], r[2], r[3]);
        *(float4*)&sA[(wave * 4 + quarter) * 64 + sub * 8 + 4] = make_float4(r[4], r[5], r[6], r[7]);
    }

#pragma unroll
    for (int h = 0; h < 4; ++h) {
        const float4* sA4 = (const float4*)&sA[(wave * 4 + h) * 64];
        float sum = 0.f;
#pragma unroll
        for (int k4 = 0; k4 < 16; ++k4) {
            float4 a4 = sA4[k4];
            sum = fmaf(a4.x, sW[(k4 * 4 + 0) * 64 + lane], sum);
            sum = fmaf(a4.y, sW[(k4 * 4 + 1) * 64 + lane], sum);
            sum = fmaf(a4.z, sW[(k4 * 4 + 2) * 64 + lane], sum);
            sum = fmaf(a4.w, sW[(k4 * 4 + 3) * 64 + lane], sum);
        }
        hw_out[(size_t)(i0 + h) * 64 + lane] = __float2half_rn(sum * dinv[i0 + h]);
    }
}

// ---------------- layer-3 gather (4 nodes/wave; fp16 conv out) ----------------
__global__ __launch_bounds__(256) void k_gather3(
        const int* __restrict__ rowptr, const int* __restrict__ col,
        const float* __restrict__ dinv, const float* __restrict__ b,
        const __half* __restrict__ hw_in, __half* __restrict__ conv) {
    int t = threadIdx.x;
    int wave = t >> 6, lane = t & 63;
    int quarter = lane >> 4, slot = (lane >> 3) & 1, sub = lane & 7;
    int i = blockIdx.x * 16 + wave * 4 + quarter;
    float di = dinv[i];
    int rs = rowptr[i], re = rowptr[i + 1];
    const uint4* hv = (const uint4*)hw_in;

    float f[8];
    gather2x4(col, hv, rs, re, slot, sub, f);

    if (slot == 0) {
        uint4 us = hv[(size_t)i * 8 + sub];
        float2 s0 = __half22float2(*(__half2*)&us.x);
        float2 s1 = __half22float2(*(__half2*)&us.y);
        float2 s2 = __half22float2(*(__half2*)&us.z);
        float2 s3 = __half22float2(*(__half2*)&us.w);
        float sf[8] = {s0.x, s0.y, s1.x, s1.y, s2.x, s2.y, s3.x, s3.y};
        float4 ba = ((const float4*)b)[sub * 2];
        float4 bb = ((const float4*)b)[sub * 2 + 1];
        float bf[8] = {ba.x, ba.y, ba.z, ba.w, bb.x, bb.y, bb.z, bb.w};
        uint4 o;
        __half2* oh = (__half2*)&o;
#pragma unroll
        for (int c = 0; c < 4; ++c) {
            float r0 = fmaf(di, f[2 * c] + sf[2 * c], bf[2 * c]);
            float r1 = fmaf(di, f[2 * c + 1] + sf[2 * c + 1], bf[2 * c + 1]);
            oh[c] = __halves2half2(__float2half_rn(r0), __float2half_rn(r1));
        }
        ((uint4*)conv)[(size_t)i * 8 + sub] = o;
    }
}

// ---------------- fused mean-pool + dense + softmax + threshold: 8 graphs/block ----------------
__global__ __launch_bounds__(256) void k_dense(
        const __half* __restrict__ conv, const int* __restrict__ gstart,
        const float* __restrict__ Wd, const float* __restrict__ bd,
        float* __restrict__ out) {
    __shared__ float sp[8][64];
    __shared__ float red[8][4];
    int t = threadIdx.x;
    int wave = t >> 6, lane = t & 63;
    int g0 = blockIdx.x * 8;
#pragma unroll
    for (int gg = 0; gg < 2; ++gg) {
        int g = wave * 2 + gg;
        int n0 = gstart[g0 + g], n1 = gstart[g0 + g + 1];
        float acc = 0.f;
        int i = n0;
        for (; i + 1 < n1; i += 2) {
            float v0 = __half2float(conv[(size_t)i * 64 + lane]);
            float v1 = __half2float(conv[(size_t)(i + 1) * 64 + lane]);
            acc += v0 + v1;
        }
        if (i < n1) acc += __half2float(conv[(size_t)i * 64 + lane]);
        int n = n1 - n0;
        sp[g][lane] = (n > 0) ? acc / (float)n : 0.f;
    }
    __syncthreads();

    float acc[8][8];
#pragma unroll
    for (int r = 0; r < 8; ++r) {
        float bv = bd[r * 256 + t];
#pragma unroll
        for (int g = 0; g < 8; ++g) acc[g][r] = bv;
    }
    for (int k = 0; k < 64; ++k) {
        float w[8];
#pragma unroll
        for (int r = 0; r < 8; ++r) w[r] = Wd[k * BIOPRINT + r * 256 + t];
#pragma unroll
        for (int g = 0; g < 8; ++g) {
            float h = sp[g][k];
#pragma unroll
            for (int r = 0; r < 8; ++r) acc[g][r] = fmaf(h, w[r], acc[g][r]);
        }
    }
    float gm[8];
#pragma unroll
    for (int g = 0; g < 8; ++g) {
        float m = acc[g][0];
#pragma unroll
        for (int r = 1; r < 8; ++r) m = fmaxf(m, acc[g][r]);
#pragma unroll
        for (int off = 32; off > 0; off >>= 1) m = fmaxf(m, __shfl_xor(m, off));
        if (lane == 0) red[g][wave] = m;
    }
    __syncthreads();
#pragma unroll
    for (int g = 0; g < 8; ++g)
        gm[g] = fmaxf(fmaxf(red[g][0], red[g][1]), fmaxf(red[g][2], red[g][3]));
    __syncthreads();
    float gs[8];
#pragma unroll
    for (int g = 0; g < 8; ++g) {
        float s = 0.f;
#pragma unroll
        for (int r = 0; r < 8; ++r) { acc[g][r] = expf(acc[g][r] - gm[g]); s += acc[g][r]; }
#pragma unroll
        for (int off = 32; off > 0; off >>= 1) s += __shfl_xor(s, off);
        if (lane == 0) red[g][wave] = s;
    }
    __syncthreads();
#pragma unroll
    for (int g = 0; g < 8; ++g)
        gs[g] = red[g][0] + red[g][1] + red[g][2] + red[g][3];
#pragma unroll
    for (int g = 0; g < 8; ++g)
#pragma unroll
        for (int r = 0; r < 8; ++r) {
            float p = acc[g][r] / gs[g];
            out[(size_t)(g0 + g) * BIOPRINT + r * 256 + t] = (p >= 0.5f) ? 1.0f : 0.0f;
        }
}

// ---------------- launch ----------------

extern "C" void kernel_launch(void* const* d_in, const int* in_sizes, int n_in,
                              void* d_out, int out_size, void* d_ws, size_t ws_size,
                              hipStream_t stream) {
    const float* x     = (const float*)d_in[0];
    const int*   ei    = (const int*)d_in[1];
    const int*   batch = (const int*)d_in[2];
    const float* W1 = (const float*)d_in[3];
    const float* b1 = (const float*)d_in[4];
    const float* W2 = (const float*)d_in[5];
    const float* b2 = (const float*)d_in[6];
    const float* W3 = (const float*)d_in[7];
    const float* b3 = (const float*)d_in[8];
    const float* Wd = (const float*)d_in[9];
    const float* bd = (const float*)d_in[10];
    float* out = (float*)d_out;

    const int* src = ei;
    const int* dst = ei + N_EDGES;

    char* ws = (char*)d_ws;
    size_t off = 0;
    auto alloc = [&](size_t bytes) {
        void* p = ws + off;
        off += (bytes + 255) & ~(size_t)255;
        return p;
    };
    int*    deg    = (int*)alloc(N_NODES * sizeof(int));
    float*  dinv   = (float*)alloc(N_NODES * sizeof(float));
    int*    rowptr = (int*)alloc((N_NODES + 1) * sizeof(int));
    int*    bsum   = (int*)alloc(128 * sizeof(int));
    int*    cursor = (int*)alloc(N_NODES * sizeof(int));
    int*    gstart = (int*)alloc((N_GRAPHS + 1) * sizeof(int));
    int*    col    = (int*)alloc((size_t)N_EDGES * sizeof(int));
    __half* bufA   = (__half*)alloc((size_t)N_NODES * HIDDEN * sizeof(__half));
    __half* bufB   = (__half*)alloc((size_t)N_NODES * HIDDEN * sizeof(__half));
    __half* conv   = (__half*)alloc((size_t)N_NODES * HIDDEN * sizeof(__half));

    hipMemsetAsync(deg, 0, N_NODES * sizeof(int), stream);

    k_deg<<<(N_EDGES + 255) / 256, 256, 0, stream>>>(dst, deg, N_EDGES);
    k_scan1<<<N_SCAN_BLOCKS, SCAN_BLK, 0, stream>>>(deg, rowptr, bsum, dinv, N_NODES);
    k_scan3<<<N_SCAN_BLOCKS + 2, SCAN_BLK, 0, stream>>>(rowptr, deg, bsum, cursor,
                                                        batch, gstart, N_NODES);
    for (int p = 0; p < 2; ++p) {
        k_fillp<<<(N_EDGES + 255) / 256, 256, 0, stream>>>(
            src, dst, cursor, col, p * FILL_SLICE, (p + 1) * FILL_SLICE, N_EDGES);
    }

    const int mm_grid  = N_NODES / 4;          // 25000
    const int g16_grid = N_NODES / 16;         // 6250 (16 nodes/block)
    k_mm<<<mm_grid, 256, 0, stream>>>(x, W1, dinv, bufA);
    k_gmm<<<g16_grid, 256, 0, stream>>>(rowptr, col, dinv, b1, bufA, W2, bufB);
    k_gmm<<<g16_grid, 256, 0, stream>>>(rowptr, col, dinv, b2, bufB, W3, bufA);
    k_gather3<<<g16_grid, 256, 0, stream>>>(rowptr, col, dinv, b3, bufA, conv);
    k_dense<<<N_GRAPHS / 8, 256, 0, stream>>>(conv, gstart, Wd, bd, out);
}

// Round 18
// 501.003 us; speedup vs baseline: 1.1212x; 1.0425x over previous
//
#include <hip/hip_runtime.h>
#include <hip/hip_fp16.h>
#include <math.h>

#define N_NODES   100000
#define N_EDGES   1600000
#define N_FEAT    64
#define HIDDEN    64
#define BIOPRINT  2048
#define N_GRAPHS  1024

#define SCAN_BLK  1024
#define N_SCAN_BLOCKS ((N_NODES + SCAN_BLK - 1) / SCAN_BLK)   // 98
#define XCD_SLICE 12500                                        // nodes per XCD slice
#define FILL_BLOCKS 2000                                       // 250 blocks x 8 slices
#define SLICE_THREADS (250 * 256)                              // threads per slice

__device__ __forceinline__ __half2 shx_h2(__half2 v, int m) {
    int x = __shfl_xor(*(int*)&v, m);
    return *(__half2*)&x;
}

// ---------------- degree: XCD-sliced (slice p owns deg[12500p..12500(p+1)) ) ----------------
// blockIdx&7 -> XCD (round-robin dispatch); each slice strides the whole edge
// list; its 50KB deg slice stays in one XCD's L2 (no cross-XCD line ping-pong).

__global__ void k_deg(const int* __restrict__ dst, int* __restrict__ deg) {
    int p = blockIdx.x & 7;
    int lo = p * XCD_SLICE, hi = lo + XCD_SLICE;
    int e0 = (blockIdx.x >> 3) * 256 + threadIdx.x;
    for (int e = e0; e < N_EDGES; e += SLICE_THREADS) {
        int d = __builtin_nontemporal_load(&dst[e]);
        if (d >= lo && d < hi) atomicAdd(&deg[d], 1);
    }
}

// ---------------- CSR build: scan1 (+dinv), scan3 (+inline bsum scan, +gstart) ----------------

__global__ __launch_bounds__(SCAN_BLK) void k_scan1(
        const int* __restrict__ deg, int* __restrict__ incl,
        int* __restrict__ bsum, float* __restrict__ dinv, int n) {
    __shared__ int tmp[SCAN_BLK];
    int t = threadIdx.x;
    int i = blockIdx.x * SCAN_BLK + t;
    int v = (i < n) ? deg[i] : 0;
    if (i < n) dinv[i] = rsqrtf((float)v + 1.0f);
    tmp[t] = v;
    __syncthreads();
    for (int off = 1; off < SCAN_BLK; off <<= 1) {
        int u = (t >= off) ? tmp[t - off] : 0;
        __syncthreads();
        tmp[t] += u;
        __syncthreads();
    }
    if (i < n) incl[i] = tmp[t];
    if (t == SCAN_BLK - 1) bsum[blockIdx.x] = tmp[t];
}

__global__ __launch_bounds__(SCAN_BLK) void k_scan3(
        int* __restrict__ rowptr, const int* __restrict__ deg,
        const int* __restrict__ bsum, int* __restrict__ cursor,
        const int* __restrict__ batch, int* __restrict__ gstart, int n) {
    int t = threadIdx.x;
    int bid = blockIdx.x;
    if (bid >= N_SCAN_BLOCKS) {
        int g = (bid - N_SCAN_BLOCKS) * SCAN_BLK + t;
        if (g > N_GRAPHS) return;
        if (g == N_GRAPHS) { gstart[g] = N_NODES; return; }
        int lo = 0, hi = N_NODES;
        while (lo < hi) { int mid = (lo + hi) >> 1; if (batch[mid] < g) lo = mid + 1; else hi = mid; }
        gstart[g] = lo;
        return;
    }
    __shared__ int sb[128];
    if (t < 128) sb[t] = (t < N_SCAN_BLOCKS) ? bsum[t] : 0;
    __syncthreads();
    for (int off = 1; off < 128; off <<= 1) {
        int u = (t >= off && t < 128) ? sb[t - off] : 0;
        __syncthreads();
        if (t < 128) sb[t] += u;
        __syncthreads();
    }
    int base = (bid == 0) ? 0 : sb[bid - 1];
    int i = bid * SCAN_BLK + t;
    if (i < n) {
        int ex = rowptr[i] - deg[i] + base;
        rowptr[i] = ex;
        cursor[i] = ex;
    }
    if (i == 0) rowptr[n] = N_EDGES;
}

// ---------------- fill: XCD-sliced single pass ----------------
// Slice p owns dst range [12500p, 12500(p+1)): its 800KB col slice + 50KB
// cursor slice stay in one XCD's L2; each line written back once.
__global__ void k_fillx(const int* __restrict__ src, const int* __restrict__ dst,
                        int* __restrict__ cursor, int* __restrict__ col) {
    int p = blockIdx.x & 7;
    int lo = p * XCD_SLICE, hi = lo + XCD_SLICE;
    int e0 = (blockIdx.x >> 3) * 256 + threadIdx.x;
    for (int e = e0; e < N_EDGES; e += SLICE_THREADS) {
        int d = __builtin_nontemporal_load(&dst[e]);
        if (d >= lo && d < hi) {
            int s = __builtin_nontemporal_load(&src[e]);
            int pos = atomicAdd(&cursor[d], 1);
            col[pos] = s;
        }
    }
}

// ---------------- layer-1 matmul: hw1' = fp16[(x @ W1) * dinv] ----------------
__global__ __launch_bounds__(256) void k_mm(
        const float* __restrict__ h, const float* __restrict__ W,
        const float* __restrict__ dinv, __half* __restrict__ hw) {
    __shared__ float sW[64 * 64];
    __shared__ float sH[4 * 64];
    int t = threadIdx.x;
    const float4* W4 = (const float4*)W;
    float4* sW4 = (float4*)sW;
    for (int i = t; i < 1024; i += 256) sW4[i] = W4[i];
    int row0 = blockIdx.x * 4;
    int r = t >> 6, j = t & 63;
    sH[r * 64 + j] = h[(row0 + r) * 64 + j];
    __syncthreads();
    int i = row0 + r;
    float sum = 0.0f;
#pragma unroll
    for (int k = 0; k < 64; ++k) sum = fmaf(sH[r * 64 + k], sW[k * 64 + j], sum);
    hw[i * 64 + j] = __float2half_rn(sum * dinv[i]);
}

// ---------------- gather core: 4 nodes per wave, 2 slots/node, 4 loads in flight ----------------
__device__ __forceinline__ void gather2x4(
        const int* __restrict__ col, const uint4* __restrict__ hv,
        int rs, int re, int slot, int sub, float f[8]) {
    __half2 a0 = __float2half2_rn(0.f), a1 = a0, a2 = a0, a3 = a0;
    __half2 c0 = a0, c1 = a0, c2 = a0, c3 = a0;
    int e = rs;
    for (; e + 8 <= re; e += 8) {
        int s0 = __builtin_nontemporal_load(&col[e + slot]);
        int s1 = __builtin_nontemporal_load(&col[e + 2 + slot]);
        int s2 = __builtin_nontemporal_load(&col[e + 4 + slot]);
        int s3 = __builtin_nontemporal_load(&col[e + 6 + slot]);
        uint4 u0 = hv[(size_t)s0 * 8 + sub];
        uint4 u1 = hv[(size_t)s1 * 8 + sub];
        uint4 u2 = hv[(size_t)s2 * 8 + sub];
        uint4 u3 = hv[(size_t)s3 * 8 + sub];
        a0 = __hadd2(a0, *(__half2*)&u0.x); a1 = __hadd2(a1, *(__half2*)&u0.y);
        a2 = __hadd2(a2, *(__half2*)&u0.z); a3 = __hadd2(a3, *(__half2*)&u0.w);
        c0 = __hadd2(c0, *(__half2*)&u1.x); c1 = __hadd2(c1, *(__half2*)&u1.y);
        c2 = __hadd2(c2, *(__half2*)&u1.z); c3 = __hadd2(c3, *(__half2*)&u1.w);
        a0 = __hadd2(a0, *(__half2*)&u2.x); a1 = __hadd2(a1, *(__half2*)&u2.y);
        a2 = __hadd2(a2, *(__half2*)&u2.z); a3 = __hadd2(a3, *(__half2*)&u2.w);
        c0 = __hadd2(c0, *(__half2*)&u3.x); c1 = __hadd2(c1, *(__half2*)&u3.y);
        c2 = __hadd2(c2, *(__half2*)&u3.z); c3 = __hadd2(c3, *(__half2*)&u3.w);
    }
    for (; e + slot < re; e += 2) {
        int s0 = col[e + slot];
        uint4 u0 = hv[(size_t)s0 * 8 + sub];
        a0 = __hadd2(a0, *(__half2*)&u0.x); a1 = __hadd2(a1, *(__half2*)&u0.y);
        a2 = __hadd2(a2, *(__half2*)&u0.z); a3 = __hadd2(a3, *(__half2*)&u0.w);
    }
    a0 = __hadd2(a0, c0); a1 = __hadd2(a1, c1);
    a2 = __hadd2(a2, c2); a3 = __hadd2(a3, c3);
    a0 = __hadd2(a0, shx_h2(a0, 8));
    a1 = __hadd2(a1, shx_h2(a1, 8));
    a2 = __hadd2(a2, shx_h2(a2, 8));
    a3 = __hadd2(a3, shx_h2(a3, 8));
    float2 f0 = __half22float2(a0), f1 = __half22float2(a1);
    float2 f2 = __half22float2(a2), f3 = __half22float2(a3);
    f[0] = f0.x; f[1] = f0.y; f[2] = f1.x; f[3] = f1.y;
    f[4] = f2.x; f[5] = f2.y; f[6] = f3.x; f[7] = f3.y;
}

// ---------------- fused gather(4 nodes/wave) + relu + LDS matmul ----------------
__global__ __launch_bounds__(256) void k_gmm(
        const int* __restrict__ rowptr, const int* __restrict__ col,
        const float* __restrict__ dinv, const float* __restrict__ b,
        const __half* __restrict__ hw_in, const float* __restrict__ W,
        __half* __restrict__ hw_out) {
    __shared__ float sW[64 * 64];
    __shared__ float sA[16 * 64];
    int t = threadIdx.x;
    const float4* W4 = (const float4*)W;
    float4* sW4 = (float4*)sW;
    for (int i = t; i < 1024; i += 256) sW4[i] = W4[i];
    __syncthreads();

    int wave = t >> 6, lane = t & 63;
    int quarter = lane >> 4, slot = (lane >> 3) & 1, sub = lane & 7;
    int i0 = blockIdx.x * 16 + wave * 4;
    int i = i0 + quarter;
    float di = dinv[i];
    int rs = rowptr[i], re = rowptr[i + 1];
    const uint4* hv = (const uint4*)hw_in;

    float f[8];
    gather2x4(col, hv, rs, re, slot, sub, f);

    uint4 us = hv[(size_t)i * 8 + sub];
    float2 s0 = __half22float2(*(__half2*)&us.x);
    float2 s1 = __half22float2(*(__half2*)&us.y);
    float2 s2 = __half22float2(*(__half2*)&us.z);
    float2 s3 = __half22float2(*(__half2*)&us.w);
    float sf[8] = {s0.x, s0.y, s1.x, s1.y, s2.x, s2.y, s3.x, s3.y};
    float4 ba = ((const float4*)b)[sub * 2];
    float4 bb = ((const float4*)b)[sub * 2 + 1];
    float bf[8] = {ba.x, ba.y, ba.z, ba.w, bb.x, bb.y, bb.z, bb.w};
    if (slot == 0) {
        float r[8];
#pragma unroll
        for (int k = 0; k < 8; ++k) r[k] = fmaxf(fmaf(di, f[k] + sf[k], bf[k]), 0.f);
        *(float4*)&sA[(wave * 4 + quarter) * 64 + sub * 8]     = make_float4(r[0], r[1], r[2], r[3]);
        *(float4*)&sA[(wave * 4 + quarter) * 64 + sub * 8 + 4] = make_float4(r[4], r[5], r[6], r[7]);
    }

#pragma unroll
    for (int h = 0; h < 4; ++h) {
        const float4* sA4 = (const float4*)&sA[(wave * 4 + h) * 64];
        float sum = 0.f;
#pragma unroll
        for (int k4 = 0; k4 < 16; ++k4) {
            float4 a4 = sA4[k4];
            sum = fmaf(a4.x, sW[(k4 * 4 + 0) * 64 + lane], sum);
            sum = fmaf(a4.y, sW[(k4 * 4 + 1) * 64 + lane], sum);
            sum = fmaf(a4.z, sW[(k4 * 4 + 2) * 64 + lane], sum);
            sum = fmaf(a4.w, sW[(k4 * 4 + 3) * 64 + lane], sum);
        }
        hw_out[(size_t)(i0 + h) * 64 + lane] = __float2half_rn(sum * dinv[i0 + h]);
    }
}

// ---------------- layer-3 gather (4 nodes/wave; fp16 conv out) ----------------
__global__ __launch_bounds__(256) void k_gather3(
        const int* __restrict__ rowptr, const int* __restrict__ col,
        const float* __restrict__ dinv, const float* __restrict__ b,
        const __half* __restrict__ hw_in, __half* __restrict__ conv) {
    int t = threadIdx.x;
    int wave = t >> 6, lane = t & 63;
    int quarter = lane >> 4, slot = (lane >> 3) & 1, sub = lane & 7;
    int i = blockIdx.x * 16 + wave * 4 + quarter;
    float di = dinv[i];
    int rs = rowptr[i], re = rowptr[i + 1];
    const uint4* hv = (const uint4*)hw_in;

    float f[8];
    gather2x4(col, hv, rs, re, slot, sub, f);

    if (slot == 0) {
        uint4 us = hv[(size_t)i * 8 + sub];
        float2 s0 = __half22float2(*(__half2*)&us.x);
        float2 s1 = __half22float2(*(__half2*)&us.y);
        float2 s2 = __half22float2(*(__half2*)&us.z);
        float2 s3 = __half22float2(*(__half2*)&us.w);
        float sf[8] = {s0.x, s0.y, s1.x, s1.y, s2.x, s2.y, s3.x, s3.y};
        float4 ba = ((const float4*)b)[sub * 2];
        float4 bb = ((const float4*)b)[sub * 2 + 1];
        float bf[8] = {ba.x, ba.y, ba.z, ba.w, bb.x, bb.y, bb.z, bb.w};
        uint4 o;
        __half2* oh = (__half2*)&o;
#pragma unroll
        for (int c = 0; c < 4; ++c) {
            float r0 = fmaf(di, f[2 * c] + sf[2 * c], bf[2 * c]);
            float r1 = fmaf(di, f[2 * c + 1] + sf[2 * c + 1], bf[2 * c + 1]);
            oh[c] = __halves2half2(__float2half_rn(r0), __float2half_rn(r1));
        }
        ((uint4*)conv)[(size_t)i * 8 + sub] = o;
    }
}

// ---------------- fused mean-pool + dense + softmax + threshold: 8 graphs/block ----------------
__global__ __launch_bounds__(256) void k_dense(
        const __half* __restrict__ conv, const int* __restrict__ gstart,
        const float* __restrict__ Wd, const float* __restrict__ bd,
        float* __restrict__ out) {
    __shared__ float sp[8][64];
    __shared__ float red[8][4];
    int t = threadIdx.x;
    int wave = t >> 6, lane = t & 63;
    int g0 = blockIdx.x * 8;
#pragma unroll
    for (int gg = 0; gg < 2; ++gg) {
        int g = wave * 2 + gg;
        int n0 = gstart[g0 + g], n1 = gstart[g0 + g + 1];
        float acc = 0.f;
        int i = n0;
        for (; i + 1 < n1; i += 2) {
            float v0 = __half2float(conv[(size_t)i * 64 + lane]);
            float v1 = __half2float(conv[(size_t)(i + 1) * 64 + lane]);
            acc += v0 + v1;
        }
        if (i < n1) acc += __half2float(conv[(size_t)i * 64 + lane]);
        int n = n1 - n0;
        sp[g][lane] = (n > 0) ? acc / (float)n : 0.f;
    }
    __syncthreads();

    float acc[8][8];
#pragma unroll
    for (int r = 0; r < 8; ++r) {
        float bv = bd[r * 256 + t];
#pragma unroll
        for (int g = 0; g < 8; ++g) acc[g][r] = bv;
    }
    for (int k = 0; k < 64; ++k) {
        float w[8];
#pragma unroll
        for (int r = 0; r < 8; ++r) w[r] = Wd[k * BIOPRINT + r * 256 + t];
#pragma unroll
        for (int g = 0; g < 8; ++g) {
            float h = sp[g][k];
#pragma unroll
            for (int r = 0; r < 8; ++r) acc[g][r] = fmaf(h, w[r], acc[g][r]);
        }
    }
    float gm[8];
#pragma unroll
    for (int g = 0; g < 8; ++g) {
        float m = acc[g][0];
#pragma unroll
        for (int r = 1; r < 8; ++r) m = fmaxf(m, acc[g][r]);
#pragma unroll
        for (int off = 32; off > 0; off >>= 1) m = fmaxf(m, __shfl_xor(m, off));
        if (lane == 0) red[g][wave] = m;
    }
    __syncthreads();
#pragma unroll
    for (int g = 0; g < 8; ++g)
        gm[g] = fmaxf(fmaxf(red[g][0], red[g][1]), fmaxf(red[g][2], red[g][3]));
    __syncthreads();
    float gs[8];
#pragma unroll
    for (int g = 0; g < 8; ++g) {
        float s = 0.f;
#pragma unroll
        for (int r = 0; r < 8; ++r) { acc[g][r] = expf(acc[g][r] - gm[g]); s += acc[g][r]; }
#pragma unroll
        for (int off = 32; off > 0; off >>= 1) s += __shfl_xor(s, off);
        if (lane == 0) red[g][wave] = s;
    }
    __syncthreads();
#pragma unroll
    for (int g = 0; g < 8; ++g)
        gs[g] = red[g][0] + red[g][1] + red[g][2] + red[g][3];
#pragma unroll
    for (int g = 0; g < 8; ++g)
#pragma unroll
        for (int r = 0; r < 8; ++r) {
            float p = acc[g][r] / gs[g];
            out[(size_t)(g0 + g) * BIOPRINT + r * 256 + t] = (p >= 0.5f) ? 1.0f : 0.0f;
        }
}

// ---------------- launch ----------------

extern "C" void kernel_launch(void* const* d_in, const int* in_sizes, int n_in,
                              void* d_out, int out_size, void* d_ws, size_t ws_size,
                              hipStream_t stream) {
    const float* x     = (const float*)d_in[0];
    const int*   ei    = (const int*)d_in[1];
    const int*   batch = (const int*)d_in[2];
    const float* W1 = (const float*)d_in[3];
    const float* b1 = (const float*)d_in[4];
    const float* W2 = (const float*)d_in[5];
    const float* b2 = (const float*)d_in[6];
    const float* W3 = (const float*)d_in[7];
    const float* b3 = (const float*)d_in[8];
    const float* Wd = (const float*)d_in[9];
    const float* bd = (const float*)d_in[10];
    float* out = (float*)d_out;

    const int* src = ei;
    const int* dst = ei + N_EDGES;

    char* ws = (char*)d_ws;
    size_t off = 0;
    auto alloc = [&](size_t bytes) {
        void* p = ws + off;
        off += (bytes + 255) & ~(size_t)255;
        return p;
    };
    int*    deg    = (int*)alloc(N_NODES * sizeof(int));
    float*  dinv   = (float*)alloc(N_NODES * sizeof(float));
    int*    rowptr = (int*)alloc((N_NODES + 1) * sizeof(int));
    int*    bsum   = (int*)alloc(128 * sizeof(int));
    int*    cursor = (int*)alloc(N_NODES * sizeof(int));
    int*    gstart = (int*)alloc((N_GRAPHS + 1) * sizeof(int));
    int*    col    = (int*)alloc((size_t)N_EDGES * sizeof(int));
    __half* bufA   = (__half*)alloc((size_t)N_NODES * HIDDEN * sizeof(__half));
    __half* bufB   = (__half*)alloc((size_t)N_NODES * HIDDEN * sizeof(__half));
    __half* conv   = (__half*)alloc((size_t)N_NODES * HIDDEN * sizeof(__half));

    hipMemsetAsync(deg, 0, N_NODES * sizeof(int), stream);

    k_deg<<<FILL_BLOCKS, 256, 0, stream>>>(dst, deg);
    k_scan1<<<N_SCAN_BLOCKS, SCAN_BLK, 0, stream>>>(deg, rowptr, bsum, dinv, N_NODES);
    k_scan3<<<N_SCAN_BLOCKS + 2, SCAN_BLK, 0, stream>>>(rowptr, deg, bsum, cursor,
                                                        batch, gstart, N_NODES);
    k_fillx<<<FILL_BLOCKS, 256, 0, stream>>>(src, dst, cursor, col);

    const int mm_grid  = N_NODES / 4;          // 25000
    const int g16_grid = N_NODES / 16;         // 6250 (16 nodes/block)
    k_mm<<<mm_grid, 256, 0, stream>>>(x, W1, dinv, bufA);
    k_gmm<<<g16_grid, 256, 0, stream>>>(rowptr, col, dinv, b1, bufA, W2, bufB);
    k_gmm<<<g16_grid, 256, 0, stream>>>(rowptr, col, dinv, b2, bufB, W3, bufA);
    k_gather3<<<g16_grid, 256, 0, stream>>>(rowptr, col, dinv, b3, bufA, conv);
    k_dense<<<N_GRAPHS / 8, 256, 0, stream>>>(conv, gstart, Wd, bd, out);
}

// Round 19
// 495.024 us; speedup vs baseline: 1.1347x; 1.0121x over previous
//
#include <hip/hip_runtime.h>
#include <hip/hip_fp16.h>
#include <math.h>

#define N_NODES   100000
#define N_EDGES   1600000
#define N_FEAT    64
#define HIDDEN    64
#define BIOPRINT  2048
#define N_GRAPHS  1024

#define SCAN_BLK  1024
#define N_SCAN_BLOCKS ((N_NODES + SCAN_BLK - 1) / SCAN_BLK)   // 98
#define XCD_SLICE 12500                                        // nodes per XCD slice
#define FILL_BLOCKS 2000                                       // 250 blocks x 8 slices
#define SLICE_THREADS (250 * 256)                              // threads per slice
#define MM_GRID (N_NODES / 4)                                  // 25000

__device__ __forceinline__ __half2 shx_h2(__half2 v, int m) {
    int x = __shfl_xor(*(int*)&v, m);
    return *(__half2*)&x;
}

// ---------------- degree: 1 edge/thread (scatter is latency-bound; max waves) ----------------

__global__ void k_deg(const int* __restrict__ dst, int* __restrict__ deg, int n) {
    int i = blockIdx.x * blockDim.x + threadIdx.x;
    if (i < n) atomicAdd(&deg[__builtin_nontemporal_load(&dst[i])], 1);
}

// ---------------- CSR build: scan1 (+dinv), scan3 (+inline bsum scan, +gstart) ----------------

__global__ __launch_bounds__(SCAN_BLK) void k_scan1(
        const int* __restrict__ deg, int* __restrict__ incl,
        int* __restrict__ bsum, float* __restrict__ dinv, int n) {
    __shared__ int tmp[SCAN_BLK];
    int t = threadIdx.x;
    int i = blockIdx.x * SCAN_BLK + t;
    int v = (i < n) ? deg[i] : 0;
    if (i < n) dinv[i] = rsqrtf((float)v + 1.0f);
    tmp[t] = v;
    __syncthreads();
    for (int off = 1; off < SCAN_BLK; off <<= 1) {
        int u = (t >= off) ? tmp[t - off] : 0;
        __syncthreads();
        tmp[t] += u;
        __syncthreads();
    }
    if (i < n) incl[i] = tmp[t];
    if (t == SCAN_BLK - 1) bsum[blockIdx.x] = tmp[t];
}

__global__ __launch_bounds__(SCAN_BLK) void k_scan3(
        int* __restrict__ rowptr, const int* __restrict__ deg,
        const int* __restrict__ bsum, int* __restrict__ cursor,
        const int* __restrict__ batch, int* __restrict__ gstart, int n) {
    int t = threadIdx.x;
    int bid = blockIdx.x;
    if (bid >= N_SCAN_BLOCKS) {
        int g = (bid - N_SCAN_BLOCKS) * SCAN_BLK + t;
        if (g > N_GRAPHS) return;
        if (g == N_GRAPHS) { gstart[g] = N_NODES; return; }
        int lo = 0, hi = N_NODES;
        while (lo < hi) { int mid = (lo + hi) >> 1; if (batch[mid] < g) lo = mid + 1; else hi = mid; }
        gstart[g] = lo;
        return;
    }
    __shared__ int sb[128];
    if (t < 128) sb[t] = (t < N_SCAN_BLOCKS) ? bsum[t] : 0;
    __syncthreads();
    for (int off = 1; off < 128; off <<= 1) {
        int u = (t >= off && t < 128) ? sb[t - off] : 0;
        __syncthreads();
        if (t < 128) sb[t] += u;
        __syncthreads();
    }
    int base = (bid == 0) ? 0 : sb[bid - 1];
    int i = bid * SCAN_BLK + t;
    if (i < n) {
        int ex = rowptr[i] - deg[i] + base;
        rowptr[i] = ex;
        cursor[i] = ex;
    }
    if (i == 0) rowptr[n] = N_EDGES;
}

// ---------------- fat kernel: XCD-sliced fill + layer-1 matmul ----------------
// Blocks [0, FILL_BLOCKS): fill slice p=bid&7 (dst in [12500p,12500(p+1))).
// Blocks [FILL_BLOCKS, FILL_BLOCKS+MM_GRID): hw1' = fp16[(x @ W1) * dinv].
// Independent work co-scheduled: VALU-heavy mm hides inside latency-bound fill.
__global__ __launch_bounds__(256) void k_fillmm(
        const int* __restrict__ src, const int* __restrict__ dst,
        int* __restrict__ cursor, int* __restrict__ col,
        const float* __restrict__ h, const float* __restrict__ W,
        const float* __restrict__ dinv, __half* __restrict__ hw) {
    int bid = blockIdx.x;
    if (bid < FILL_BLOCKS) {
        int p = bid & 7;
        int lo = p * XCD_SLICE, hi = lo + XCD_SLICE;
        int e0 = (bid >> 3) * 256 + threadIdx.x;
        for (int e = e0; e < N_EDGES; e += SLICE_THREADS) {
            int d = __builtin_nontemporal_load(&dst[e]);
            if (d >= lo && d < hi) {
                int s = __builtin_nontemporal_load(&src[e]);
                int pos = atomicAdd(&cursor[d], 1);
                col[pos] = s;
            }
        }
        return;
    }
    __shared__ float sW[64 * 64];
    __shared__ float sH[4 * 64];
    int t = threadIdx.x;
    const float4* W4 = (const float4*)W;
    float4* sW4 = (float4*)sW;
    for (int i = t; i < 1024; i += 256) sW4[i] = W4[i];
    int row0 = (bid - FILL_BLOCKS) * 4;
    int r = t >> 6, j = t & 63;
    sH[r * 64 + j] = h[(row0 + r) * 64 + j];
    __syncthreads();
    int i = row0 + r;
    float sum = 0.0f;
#pragma unroll
    for (int k = 0; k < 64; ++k) sum = fmaf(sH[r * 64 + k], sW[k * 64 + j], sum);
    hw[i * 64 + j] = __float2half_rn(sum * dinv[i]);
}

// ---------------- gather core: 4 nodes per wave, 2 slots/node, 4 loads in flight ----------------
__device__ __forceinline__ void gather2x4(
        const int* __restrict__ col, const uint4* __restrict__ hv,
        int rs, int re, int slot, int sub, float f[8]) {
    __half2 a0 = __float2half2_rn(0.f), a1 = a0, a2 = a0, a3 = a0;
    __half2 c0 = a0, c1 = a0, c2 = a0, c3 = a0;
    int e = rs;
    for (; e + 8 <= re; e += 8) {
        int s0 = __builtin_nontemporal_load(&col[e + slot]);
        int s1 = __builtin_nontemporal_load(&col[e + 2 + slot]);
        int s2 = __builtin_nontemporal_load(&col[e + 4 + slot]);
        int s3 = __builtin_nontemporal_load(&col[e + 6 + slot]);
        uint4 u0 = hv[(size_t)s0 * 8 + sub];
        uint4 u1 = hv[(size_t)s1 * 8 + sub];
        uint4 u2 = hv[(size_t)s2 * 8 + sub];
        uint4 u3 = hv[(size_t)s3 * 8 + sub];
        a0 = __hadd2(a0, *(__half2*)&u0.x); a1 = __hadd2(a1, *(__half2*)&u0.y);
        a2 = __hadd2(a2, *(__half2*)&u0.z); a3 = __hadd2(a3, *(__half2*)&u0.w);
        c0 = __hadd2(c0, *(__half2*)&u1.x); c1 = __hadd2(c1, *(__half2*)&u1.y);
        c2 = __hadd2(c2, *(__half2*)&u1.z); c3 = __hadd2(c3, *(__half2*)&u1.w);
        a0 = __hadd2(a0, *(__half2*)&u2.x); a1 = __hadd2(a1, *(__half2*)&u2.y);
        a2 = __hadd2(a2, *(__half2*)&u2.z); a3 = __hadd2(a3, *(__half2*)&u2.w);
        c0 = __hadd2(c0, *(__half2*)&u3.x); c1 = __hadd2(c1, *(__half2*)&u3.y);
        c2 = __hadd2(c2, *(__half2*)&u3.z); c3 = __hadd2(c3, *(__half2*)&u3.w);
    }
    for (; e + slot < re; e += 2) {
        int s0 = col[e + slot];
        uint4 u0 = hv[(size_t)s0 * 8 + sub];
        a0 = __hadd2(a0, *(__half2*)&u0.x); a1 = __hadd2(a1, *(__half2*)&u0.y);
        a2 = __hadd2(a2, *(__half2*)&u0.z); a3 = __hadd2(a3, *(__half2*)&u0.w);
    }
    a0 = __hadd2(a0, c0); a1 = __hadd2(a1, c1);
    a2 = __hadd2(a2, c2); a3 = __hadd2(a3, c3);
    a0 = __hadd2(a0, shx_h2(a0, 8));
    a1 = __hadd2(a1, shx_h2(a1, 8));
    a2 = __hadd2(a2, shx_h2(a2, 8));
    a3 = __hadd2(a3, shx_h2(a3, 8));
    float2 f0 = __half22float2(a0), f1 = __half22float2(a1);
    float2 f2 = __half22float2(a2), f3 = __half22float2(a3);
    f[0] = f0.x; f[1] = f0.y; f[2] = f1.x; f[3] = f1.y;
    f[4] = f2.x; f[5] = f2.y; f[6] = f3.x; f[7] = f3.y;
}

// ---------------- fused gather(4 nodes/wave) + relu + LDS matmul ----------------
__global__ __launch_bounds__(256) void k_gmm(
        const int* __restrict__ rowptr, const int* __restrict__ col,
        const float* __restrict__ dinv, const float* __restrict__ b,
        const __half* __restrict__ hw_in, const float* __restrict__ W,
        __half* __restrict__ hw_out) {
    __shared__ float sW[64 * 64];
    __shared__ float sA[16 * 64];
    int t = threadIdx.x;
    const float4* W4 = (const float4*)W;
    float4* sW4 = (float4*)sW;
    for (int i = t; i < 1024; i += 256) sW4[i] = W4[i];
    __syncthreads();

    int wave = t >> 6, lane = t & 63;
    int quarter = lane >> 4, slot = (lane >> 3) & 1, sub = lane & 7;
    int i0 = blockIdx.x * 16 + wave * 4;
    int i = i0 + quarter;
    float di = dinv[i];
    int rs = rowptr[i], re = rowptr[i + 1];
    const uint4* hv = (const uint4*)hw_in;

    float f[8];
    gather2x4(col, hv, rs, re, slot, sub, f);

    uint4 us = hv[(size_t)i * 8 + sub];
    float2 s0 = __half22float2(*(__half2*)&us.x);
    float2 s1 = __half22float2(*(__half2*)&us.y);
    float2 s2 = __half22float2(*(__half2*)&us.z);
    float2 s3 = __half22float2(*(__half2*)&us.w);
    float sf[8] = {s0.x, s0.y, s1.x, s1.y, s2.x, s2.y, s3.x, s3.y};
    float4 ba = ((const float4*)b)[sub * 2];
    float4 bb = ((const float4*)b)[sub * 2 + 1];
    float bf[8] = {ba.x, ba.y, ba.z, ba.w, bb.x, bb.y, bb.z, bb.w};
    if (slot == 0) {
        float r[8];
#pragma unroll
        for (int k = 0; k < 8; ++k) r[k] = fmaxf(fmaf(di, f[k] + sf[k], bf[k]), 0.f);
        *(float4*)&sA[(wave * 4 + quarter) * 64 + sub * 8]     = make_float4(r[0], r[1], r[2], r[3]);
        *(float4*)&sA[(wave * 4 + quarter) * 64 + sub * 8 + 4] = make_float4(r[4], r[5], r[6], r[7]);
    }

#pragma unroll
    for (int h = 0; h < 4; ++h) {
        const float4* sA4 = (const float4*)&sA[(wave * 4 + h) * 64];
        float sum = 0.f;
#pragma unroll
        for (int k4 = 0; k4 < 16; ++k4) {
            float4 a4 = sA4[k4];
            sum = fmaf(a4.x, sW[(k4 * 4 + 0) * 64 + lane], sum);
            sum = fmaf(a4.y, sW[(k4 * 4 + 1) * 64 + lane], sum);
            sum = fmaf(a4.z, sW[(k4 * 4 + 2) * 64 + lane], sum);
            sum = fmaf(a4.w, sW[(k4 * 4 + 3) * 64 + lane], sum);
        }
        hw_out[(size_t)(i0 + h) * 64 + lane] = __float2half_rn(sum * dinv[i0 + h]);
    }
}

// ---------------- layer-3 gather (4 nodes/wave; fp16 conv out) ----------------
__global__ __launch_bounds__(256) void k_gather3(
        const int* __restrict__ rowptr, const int* __restrict__ col,
        const float* __restrict__ dinv, const float* __restrict__ b,
        const __half* __restrict__ hw_in, __half* __restrict__ conv) {
    int t = threadIdx.x;
    int wave = t >> 6, lane = t & 63;
    int quarter = lane >> 4, slot = (lane >> 3) & 1, sub = lane & 7;
    int i = blockIdx.x * 16 + wave * 4 + quarter;
    float di = dinv[i];
    int rs = rowptr[i], re = rowptr[i + 1];
    const uint4* hv = (const uint4*)hw_in;

    float f[8];
    gather2x4(col, hv, rs, re, slot, sub, f);

    if (slot == 0) {
        uint4 us = hv[(size_t)i * 8 + sub];
        float2 s0 = __half22float2(*(__half2*)&us.x);
        float2 s1 = __half22float2(*(__half2*)&us.y);
        float2 s2 = __half22float2(*(__half2*)&us.z);
        float2 s3 = __half22float2(*(__half2*)&us.w);
        float sf[8] = {s0.x, s0.y, s1.x, s1.y, s2.x, s2.y, s3.x, s3.y};
        float4 ba = ((const float4*)b)[sub * 2];
        float4 bb = ((const float4*)b)[sub * 2 + 1];
        float bf[8] = {ba.x, ba.y, ba.z, ba.w, bb.x, bb.y, bb.z, bb.w};
        uint4 o;
        __half2* oh = (__half2*)&o;
#pragma unroll
        for (int c = 0; c < 4; ++c) {
            float r0 = fmaf(di, f[2 * c] + sf[2 * c], bf[2 * c]);
            float r1 = fmaf(di, f[2 * c + 1] + sf[2 * c + 1], bf[2 * c + 1]);
            oh[c] = __halves2half2(__float2half_rn(r0), __float2half_rn(r1));
        }
        ((uint4*)conv)[(size_t)i * 8 + sub] = o;
    }
}

// ---------------- fused mean-pool + dense + softmax + threshold: 8 graphs/block ----------------
__global__ __launch_bounds__(256) void k_dense(
        const __half* __restrict__ conv, const int* __restrict__ gstart,
        const float* __restrict__ Wd, const float* __restrict__ bd,
        float* __restrict__ out) {
    __shared__ float sp[8][64];
    __shared__ float red[8][4];
    int t = threadIdx.x;
    int wave = t >> 6, lane = t & 63;
    int g0 = blockIdx.x * 8;
#pragma unroll
    for (int gg = 0; gg < 2; ++gg) {
        int g = wave * 2 + gg;
        int n0 = gstart[g0 + g], n1 = gstart[g0 + g + 1];
        float acc = 0.f;
        int i = n0;
        for (; i + 1 < n1; i += 2) {
            float v0 = __half2float(conv[(size_t)i * 64 + lane]);
            float v1 = __half2float(conv[(size_t)(i + 1) * 64 + lane]);
            acc += v0 + v1;
        }
        if (i < n1) acc += __half2float(conv[(size_t)i * 64 + lane]);
        int n = n1 - n0;
        sp[g][lane] = (n > 0) ? acc / (float)n : 0.f;
    }
    __syncthreads();

    float acc[8][8];
#pragma unroll
    for (int r = 0; r < 8; ++r) {
        float bv = bd[r * 256 + t];
#pragma unroll
        for (int g = 0; g < 8; ++g) acc[g][r] = bv;
    }
    for (int k = 0; k < 64; ++k) {
        float w[8];
#pragma unroll
        for (int r = 0; r < 8; ++r) w[r] = Wd[k * BIOPRINT + r * 256 + t];
#pragma unroll
        for (int g = 0; g < 8; ++g) {
            float h = sp[g][k];
#pragma unroll
            for (int r = 0; r < 8; ++r) acc[g][r] = fmaf(h, w[r], acc[g][r]);
        }
    }
    float gm[8];
#pragma unroll
    for (int g = 0; g < 8; ++g) {
        float m = acc[g][0];
#pragma unroll
        for (int r = 1; r < 8; ++r) m = fmaxf(m, acc[g][r]);
#pragma unroll
        for (int off = 32; off > 0; off >>= 1) m = fmaxf(m, __shfl_xor(m, off));
        if (lane == 0) red[g][wave] = m;
    }
    __syncthreads();
#pragma unroll
    for (int g = 0; g < 8; ++g)
        gm[g] = fmaxf(fmaxf(red[g][0], red[g][1]), fmaxf(red[g][2], red[g][3]));
    __syncthreads();
    float gs[8];
#pragma unroll
    for (int g = 0; g < 8; ++g) {
        float s = 0.f;
#pragma unroll
        for (int r = 0; r < 8; ++r) { acc[g][r] = expf(acc[g][r] - gm[g]); s += acc[g][r]; }
#pragma unroll
        for (int off = 32; off > 0; off >>= 1) s += __shfl_xor(s, off);
        if (lane == 0) red[g][wave] = s;
    }
    __syncthreads();
#pragma unroll
    for (int g = 0; g < 8; ++g)
        gs[g] = red[g][0] + red[g][1] + red[g][2] + red[g][3];
#pragma unroll
    for (int g = 0; g < 8; ++g)
#pragma unroll
        for (int r = 0; r < 8; ++r) {
            float p = acc[g][r] / gs[g];
            out[(size_t)(g0 + g) * BIOPRINT + r * 256 + t] = (p >= 0.5f) ? 1.0f : 0.0f;
        }
}

// ---------------- launch ----------------

extern "C" void kernel_launch(void* const* d_in, const int* in_sizes, int n_in,
                              void* d_out, int out_size, void* d_ws, size_t ws_size,
                              hipStream_t stream) {
    const float* x     = (const float*)d_in[0];
    const int*   ei    = (const int*)d_in[1];
    const int*   batch = (const int*)d_in[2];
    const float* W1 = (const float*)d_in[3];
    const float* b1 = (const float*)d_in[4];
    const float* W2 = (const float*)d_in[5];
    const float* b2 = (const float*)d_in[6];
    const float* W3 = (const float*)d_in[7];
    const float* b3 = (const float*)d_in[8];
    const float* Wd = (const float*)d_in[9];
    const float* bd = (const float*)d_in[10];
    float* out = (float*)d_out;

    const int* src = ei;
    const int* dst = ei + N_EDGES;

    char* ws = (char*)d_ws;
    size_t off = 0;
    auto alloc = [&](size_t bytes) {
        void* p = ws + off;
        off += (bytes + 255) & ~(size_t)255;
        return p;
    };
    int*    deg    = (int*)alloc(N_NODES * sizeof(int));
    float*  dinv   = (float*)alloc(N_NODES * sizeof(float));
    int*    rowptr = (int*)alloc((N_NODES + 1) * sizeof(int));
    int*    bsum   = (int*)alloc(128 * sizeof(int));
    int*    cursor = (int*)alloc(N_NODES * sizeof(int));
    int*    gstart = (int*)alloc((N_GRAPHS + 1) * sizeof(int));
    int*    col    = (int*)alloc((size_t)N_EDGES * sizeof(int));
    __half* bufA   = (__half*)alloc((size_t)N_NODES * HIDDEN * sizeof(__half));
    __half* bufB   = (__half*)alloc((size_t)N_NODES * HIDDEN * sizeof(__half));
    __half* conv   = (__half*)alloc((size_t)N_NODES * HIDDEN * sizeof(__half));

    hipMemsetAsync(deg, 0, N_NODES * sizeof(int), stream);

    k_deg<<<(N_EDGES + 255) / 256, 256, 0, stream>>>(dst, deg, N_EDGES);
    k_scan1<<<N_SCAN_BLOCKS, SCAN_BLK, 0, stream>>>(deg, rowptr, bsum, dinv, N_NODES);
    k_scan3<<<N_SCAN_BLOCKS + 2, SCAN_BLK, 0, stream>>>(rowptr, deg, bsum, cursor,
                                                        batch, gstart, N_NODES);
    // fill + layer-1 matmul fused (independent work, co-scheduled)
    k_fillmm<<<FILL_BLOCKS + MM_GRID, 256, 0, stream>>>(src, dst, cursor, col,
                                                        x, W1, dinv, bufA);

    const int g16_grid = N_NODES / 16;         // 6250 (16 nodes/block)
    k_gmm<<<g16_grid, 256, 0, stream>>>(rowptr, col, dinv, b1, bufA, W2, bufB);
    k_gmm<<<g16_grid, 256, 0, stream>>>(rowptr, col, dinv, b2, bufB, W3, bufA);
    k_gather3<<<g16_grid, 256, 0, stream>>>(rowptr, col, dinv, b3, bufA, conv);
    k_dense<<<N_GRAPHS / 8, 256, 0, stream>>>(conv, gstart, Wd, bd, out);
}